// Round 9
// baseline (16.568 us; speedup 1.0000x reference)
//
#include <hip/hip_runtime.h>

#define NB 4
#define NGRID 512
#define NTARGET 512
#define NBASIS 8
#define NCH 8

#if defined(__has_builtin)
#if __has_builtin(__builtin_amdgcn_exp2f)
#define EXP2F(x) __builtin_amdgcn_exp2f(x)
#else
#define EXP2F(x) exp2f(x)
#endif
#else
#define EXP2F(x) exp2f(x)
#endif

// 256 blocks x 1024 threads (16 waves) = 1 block/CU, 4 waves/SIMD.
// Block = (b, 8-target tile). Wave w: target = tile*8 + (w>>1), g-half = w&1.
// x-values for phase 2 are prefetched into registers BEFORE phase 1, so their
// global-load latency hides under the staging FMAs.
// Phase 1: block stages hw[g,c] = sum_k W[k]*h[b,g,k,c] into LDS (scalar form).
// Phase 2: pure LDS + VALU/trans exp loop; 3 shuffles once; LDS combine.
__global__ __launch_bounds__(1024) void final_layer_fused(
    const float* __restrict__ x_grid,    // (B, G, C)
    const float* __restrict__ h_grid,    // (B, G, K, C)
    const float* __restrict__ target_x,  // (B, T, C)
    const float* __restrict__ W,         // (1, K)
    const float* __restrict__ bias,      // (1,)
    const float* __restrict__ sigma,     // (K, C)
    float* __restrict__ out)             // (B, T, C)
{
    __shared__ float shw[NGRID * NCH];   // 16 KB: shw[g*8+c]
    __shared__ float lds[16 * 8];        // [wave][c] partials

    const int tid = threadIdx.x;
    const int l   = tid & 63;
    const int w   = tid >> 6;        // 0..15
    const int c   = l & 7;

    const int bi   = blockIdx.x;
    const int b    = bi >> 6;        // 64 tiles per batch
    const int tt   = (bi & 63) * 8;  // first target of tile
    const int tl   = w >> 1;         // local target 0..7
    const int t    = tt + tl;
    const int half = w & 1;          // g-half 0/1

    const float LOG2E = 1.4426950408889634f;

    float sg = sigma[l];             // sigma viewed as [k][c] by lane
    float s0 = sigma[c];             // sigma[0][c]
    bool uniform = __all(sg == s0);  // lengthscales uniform across k?

    float tx = target_x[((size_t)b * NTARGET + t) * NCH + c];
    float b0 = bias[0];

    const float* hb = h_grid + (size_t)b * NGRID * 64;
    const size_t bbase = (size_t)b * NGRID * NCH + (size_t)half * (NGRID / 2) * NCH;
    const float* xb = x_grid + bbase;

    float v;
    if (uniform) {
        // ---- Prefetch phase-2 x values into registers (issue before staging) ----
        float xr[32];
#pragma unroll
        for (int j = 0; j < 32; ++j)
            xr[j] = xb[64 * j + l];          // fully unrolled -> stays in VGPRs

        // ---- Phase 1: stage hw into LDS; 4 values/thread, 8-FMA k-loop ----
        float w0 = W[0], w1 = W[1], w2 = W[2], w3 = W[3];
        float w4 = W[4], w5 = W[5], w6 = W[6], w7 = W[7];
#pragma unroll
        for (int vi = 0; vi < 4; ++vi) {
            int f = tid + vi * 1024;          // 0..4095 = g*8 + c
            const float* hp = hb + (size_t)(f >> 3) * 64 + (f & 7);
            float acc;
            acc = w0 * hp[0];
            acc = fmaf(w1, hp[8],  acc);
            acc = fmaf(w2, hp[16], acc);
            acc = fmaf(w3, hp[24], acc);
            acc = fmaf(w4, hp[32], acc);
            acc = fmaf(w5, hp[40], acc);
            acc = fmaf(w6, hp[48], acc);
            acc = fmaf(w7, hp[56], acc);
            shw[f] = acc;
        }
        __syncthreads();

        // ---- Phase 2: pure LDS + VALU/trans (32 iters) ----
        float scale = __expf(s0) + 1e-6f;
        float coef2 = -0.5f * LOG2E / (scale * scale);
        const float* hwb = shw + half * (NGRID / 2) * NCH;

        float a0 = 0.f, a1 = 0.f, a2 = 0.f, a3 = 0.f;
#pragma unroll
        for (int j = 0; j < 32; j += 4) {
            float h0 = hwb[64 * (j + 0) + l];
            float h1 = hwb[64 * (j + 1) + l];
            float h2 = hwb[64 * (j + 2) + l];
            float h3 = hwb[64 * (j + 3) + l];
            float d0 = xr[j + 0] - tx, d1 = xr[j + 1] - tx;
            float d2 = xr[j + 2] - tx, d3 = xr[j + 3] - tx;
            a0 = fmaf(h0, EXP2F(coef2 * (d0 * d0)), a0);
            a1 = fmaf(h1, EXP2F(coef2 * (d1 * d1)), a1);
            a2 = fmaf(h2, EXP2F(coef2 * (d2 * d2)), a2);
            a3 = fmaf(h3, EXP2F(coef2 * (d3 * d3)), a3);
        }
        v = (a0 + a1) + (a2 + a3);
    } else {
        // ---- general fallback: per-(k,c) lengthscales, h read directly ----
        float coef2k[NBASIS], wv[NBASIS];
#pragma unroll
        for (int k = 0; k < NBASIS; ++k) {
            float s = __expf(sigma[k * 8 + c]) + 1e-6f;
            coef2k[k] = -0.5f * LOG2E / (s * s);
            wv[k] = W[k];
        }
        const int gs = l >> 3;
        const float* hbh = hb + (size_t)half * (NGRID / 2) * 64;
        float acc = 0.f;
        for (int j = 0; j < 32; ++j) {
            int g = j * 8 + gs;
            float xg = xb[g * 8 + c];
            float d  = xg - tx;
            float d2 = d * d;
#pragma unroll
            for (int k = 0; k < NBASIS; ++k) {
                float hv = hbh[(size_t)g * 64 + k * 8 + c];
                acc = fmaf(wv[k] * hv, EXP2F(coef2k[k] * d2), acc);
            }
        }
        v = acc;
    }

    // reduce over gs (lane bits 3..5) — 3 shuffles once per wave
    v += __shfl_xor(v, 8);
    v += __shfl_xor(v, 16);
    v += __shfl_xor(v, 32);
    if (l < 8) lds[w * 8 + l] = v;
    __syncthreads();

    // combine the two g-halves: 64 threads -> 8 targets x 8 channels
    if (tid < 64) {
        int tl2 = tid >> 3, cc = tid & 7;
        float r = lds[(tl2 * 2) * 8 + cc] + lds[(tl2 * 2 + 1) * 8 + cc] + b0;
        out[((size_t)b * NTARGET + (tt + tl2)) * NCH + cc] = r;
    }
}

extern "C" void kernel_launch(void* const* d_in, const int* in_sizes, int n_in,
                              void* d_out, int out_size, void* d_ws, size_t ws_size,
                              hipStream_t stream) {
    const float* x_grid   = (const float*)d_in[0];
    const float* h_grid   = (const float*)d_in[1];
    const float* target_x = (const float*)d_in[2];
    const float* W        = (const float*)d_in[3];
    const float* bias     = (const float*)d_in[4];
    const float* sigma    = (const float*)d_in[5];
    float* out = (float*)d_out;

    final_layer_fused<<<dim3(NB * (NTARGET / 8)), dim3(1024), 0, stream>>>(
        x_grid, h_grid, target_x, W, bias, sigma, out);
}

// Round 10
// 11.821 us; speedup vs baseline: 1.4016x; 1.4016x over previous
//
#include <hip/hip_runtime.h>

#define NB 4
#define NGRID 512
#define NTARGET 512
#define NBASIS 8
#define NCH 8

#if defined(__has_builtin)
#if __has_builtin(__builtin_amdgcn_exp2f)
#define EXP2F(x) __builtin_amdgcn_exp2f(x)
#else
#define EXP2F(x) exp2f(x)
#endif
#else
#define EXP2F(x) exp2f(x)
#endif

// 256 blocks x 1024 threads (16 waves) = 1 block/CU, 4 waves/SIMD.
// Block = (b, 8-target tile). Wave w: target = tile*8 + (w>>1), g-half = w&1.
// Phase 1: block stages hw[g,c] = sum_k W[k]*h[b,g,k,c] into LDS (scalar form).
// Phase 2: per-wave exp loop over its g-half; 3 shuffles once; LDS combine.
// NOTE (R9 post-mortem): do NOT prefetch phase-2 x into registers before
// phase 1 — vmcnt waits on oldest loads, so staging's LDS writes end up
// draining the whole x-load queue, serializing the phases (10.3 -> 16.6 us).
__global__ __launch_bounds__(1024) void final_layer_fused(
    const float* __restrict__ x_grid,    // (B, G, C)
    const float* __restrict__ h_grid,    // (B, G, K, C)
    const float* __restrict__ target_x,  // (B, T, C)
    const float* __restrict__ W,         // (1, K)
    const float* __restrict__ bias,      // (1,)
    const float* __restrict__ sigma,     // (K, C)
    float* __restrict__ out)             // (B, T, C)
{
    __shared__ float shw[NGRID * NCH];   // 16 KB: shw[g*8+c]
    __shared__ float lds[16 * 8];        // [wave][c] partials

    const int tid = threadIdx.x;
    const int l   = tid & 63;
    const int w   = tid >> 6;        // 0..15
    const int c   = l & 7;

    const int bi   = blockIdx.x;
    const int b    = bi >> 6;        // 64 tiles per batch
    const int tt   = (bi & 63) * 8;  // first target of tile
    const int tl   = w >> 1;         // local target 0..7
    const int t    = tt + tl;
    const int half = w & 1;          // g-half 0/1

    const float LOG2E = 1.4426950408889634f;

    float sg = sigma[l];             // sigma viewed as [k][c] by lane
    float s0 = sigma[c];             // sigma[0][c]
    bool uniform = __all(sg == s0);  // lengthscales uniform across k?

    float tx = target_x[((size_t)b * NTARGET + t) * NCH + c];
    float b0 = bias[0];

    const float* hb = h_grid + (size_t)b * NGRID * 64;
    const size_t bbase = (size_t)b * NGRID * NCH + (size_t)half * (NGRID / 2) * NCH;
    const float* xb = x_grid + bbase;

    float v;
    if (uniform) {
        // ---- Phase 1: stage hw into LDS; 4 values/thread, 8-FMA k-loop ----
        float w0 = W[0], w1 = W[1], w2 = W[2], w3 = W[3];
        float w4 = W[4], w5 = W[5], w6 = W[6], w7 = W[7];
#pragma unroll
        for (int vi = 0; vi < 4; ++vi) {
            int f = tid + vi * 1024;          // 0..4095 = g*8 + c
            const float* hp = hb + (size_t)(f >> 3) * 64 + (f & 7);
            float acc;
            acc = w0 * hp[0];
            acc = fmaf(w1, hp[8],  acc);
            acc = fmaf(w2, hp[16], acc);
            acc = fmaf(w3, hp[24], acc);
            acc = fmaf(w4, hp[32], acc);
            acc = fmaf(w5, hp[40], acc);
            acc = fmaf(w6, hp[48], acc);
            acc = fmaf(w7, hp[56], acc);
            shw[f] = acc;
        }
        __syncthreads();

        // ---- Phase 2: exp loop over this wave's g-half (32 iters) ----
        float scale = __expf(s0) + 1e-6f;
        float coef2 = -0.5f * LOG2E / (scale * scale);
        const float* hwb = shw + half * (NGRID / 2) * NCH;

        float a0 = 0.f, a1 = 0.f, a2 = 0.f, a3 = 0.f;
#pragma unroll
        for (int j = 0; j < 32; j += 4) {
            float x0 = xb[64 * (j + 0) + l], h0 = hwb[64 * (j + 0) + l];
            float x1 = xb[64 * (j + 1) + l], h1 = hwb[64 * (j + 1) + l];
            float x2 = xb[64 * (j + 2) + l], h2 = hwb[64 * (j + 2) + l];
            float x3 = xb[64 * (j + 3) + l], h3 = hwb[64 * (j + 3) + l];
            float d0 = x0 - tx, d1 = x1 - tx, d2 = x2 - tx, d3 = x3 - tx;
            a0 = fmaf(h0, EXP2F(coef2 * (d0 * d0)), a0);
            a1 = fmaf(h1, EXP2F(coef2 * (d1 * d1)), a1);
            a2 = fmaf(h2, EXP2F(coef2 * (d2 * d2)), a2);
            a3 = fmaf(h3, EXP2F(coef2 * (d3 * d3)), a3);
        }
        v = (a0 + a1) + (a2 + a3);
    } else {
        // ---- general fallback: per-(k,c) lengthscales, h read directly ----
        float coef2k[NBASIS], wv[NBASIS];
#pragma unroll
        for (int k = 0; k < NBASIS; ++k) {
            float s = __expf(sigma[k * 8 + c]) + 1e-6f;
            coef2k[k] = -0.5f * LOG2E / (s * s);
            wv[k] = W[k];
        }
        const int gs = l >> 3;
        const float* hbh = hb + (size_t)half * (NGRID / 2) * 64;
        float acc = 0.f;
        for (int j = 0; j < 32; ++j) {
            int g = j * 8 + gs;
            float xg = xb[g * 8 + c];
            float d  = xg - tx;
            float d2 = d * d;
#pragma unroll
            for (int k = 0; k < NBASIS; ++k) {
                float hv = hbh[(size_t)g * 64 + k * 8 + c];
                acc = fmaf(wv[k] * hv, EXP2F(coef2k[k] * d2), acc);
            }
        }
        v = acc;
    }

    // reduce over gs (lane bits 3..5) — 3 shuffles once per wave
    v += __shfl_xor(v, 8);
    v += __shfl_xor(v, 16);
    v += __shfl_xor(v, 32);
    if (l < 8) lds[w * 8 + l] = v;
    __syncthreads();

    // combine the two g-halves: 64 threads -> 8 targets x 8 channels
    if (tid < 64) {
        int tl2 = tid >> 3, cc = tid & 7;
        float r = lds[(tl2 * 2) * 8 + cc] + lds[(tl2 * 2 + 1) * 8 + cc] + b0;
        out[((size_t)b * NTARGET + (tt + tl2)) * NCH + cc] = r;
    }
}

extern "C" void kernel_launch(void* const* d_in, const int* in_sizes, int n_in,
                              void* d_out, int out_size, void* d_ws, size_t ws_size,
                              hipStream_t stream) {
    const float* x_grid   = (const float*)d_in[0];
    const float* h_grid   = (const float*)d_in[1];
    const float* target_x = (const float*)d_in[2];
    const float* W        = (const float*)d_in[3];
    const float* bias     = (const float*)d_in[4];
    const float* sigma    = (const float*)d_in[5];
    float* out = (float*)d_out;

    final_layer_fused<<<dim3(NB * (NTARGET / 8)), dim3(1024), 0, stream>>>(
        x_grid, h_grid, target_x, W, bias, sigma, out);
}